// Round 18
// baseline (56.922 us; speedup 1.0000x reference)
//
#include <hip/hip_runtime.h>

#define NUM_CATEGORIES 64
#define IN_DIM 1024
#define OUT_DIM 1024
#define BATCH 32
#define SEQ 512

#define BM 256
#define BN 128
#define BK 32
#define NSTEP (IN_DIM / BK)   // 32

#define LDA 40     // bf16 elems per A row: 64B data + 16B pad = 80B stride
#define LDBW 20    // u32 words per B n-row: 16 kp words + 4 pad = 80B stride

typedef float f32x4 __attribute__((ext_vector_type(4)));
typedef float f32x2 __attribute__((ext_vector_type(2)));
typedef unsigned int u32x4 __attribute__((ext_vector_type(4)));
typedef __bf16 bf16x2 __attribute__((ext_vector_type(2)));
typedef __bf16 bf16x4 __attribute__((ext_vector_type(4)));
typedef __bf16 bf16x8 __attribute__((ext_vector_type(8)));

// 2 independent 512-thread blocks per CU (separate barrier domains -> natural
// phase stagger: block A's MFMA covers block B's stage/LDS phase, m114).
// 16 waves/CU total (4/SIMD). launch_bounds(512,4) = 4 waves/EU = 128-reg cap;
// budget: acc 64 + staging 24 + frags 20 + addr ~18 = ~126. Grid 512 = 2x256
// CUs exactly (no tail). LDS 60KB/block -> 120KB/CU.
__global__ __launch_bounds__(512, 4)
void cslinear_kernel(const float* __restrict__ x,
                     const int* __restrict__ cid,
                     const float* __restrict__ weight,
                     const float* __restrict__ bias,
                     float* __restrict__ out) {
    __shared__ unsigned short As[2][BM * LDA];   // 2 x 20 KB  [m][k] bf16
    __shared__ unsigned int   Bs[2][BN * LDBW];  // 2 x 10 KB  [n][kp] u32 words

    const int t    = threadIdx.x;
    const int lane = t & 63;
    const int w    = t >> 6;      // 0..7

    // XCD-aware remap: slot s -> XCD s%8; each XCD owns 4 whole batches
    // (16 blocks each: 2 mt x 8 nt).
    const int s    = blockIdx.x;      // 0..511
    const int xcd  = s & 7;
    const int ixd  = s >> 3;          // 0..63
    const int b    = xcd + 8 * (ixd >> 4);
    const int j    = ixd & 15;
    const int nt   = j & 7;           // 0..7
    const int mt   = j >> 3;          // 0..1

    const int c = cid[b];
    const float* Wp = weight + (size_t)c * IN_DIM * OUT_DIM + (size_t)nt * BN;
    const float* Xp = x + ((size_t)b * SEQ + (size_t)mt * BM) * IN_DIM;
    float* Op = out + ((size_t)b * SEQ + (size_t)mt * BM) * OUT_DIM + (size_t)nt * BN;

    f32x4 acc[4][4] = {};               // wave tile 64(m) x 64(n)

    const int mbase = (w >> 1) * 64;    // 0,64,128,192
    const int nbase = (w & 1) * 64;     // 0,64
    const int lrow  = lane & 15;
    const int lhi   = lane >> 4;        // 0..3

    // 1-deep staging regs (R17 pattern)
    f32x4 ra[4];                        // A: 256x32 f32 / 512 thr = 4 f32x4
    float rbf[8];                       // B: one 8-deep k-column of one n

    const int bn_n  = t & 127;          // B: this thread's n-column
    const int bn_kq = (t >> 7) & 3;     // 0..3: k-quarter (8 k-rows)

    auto LOADT = [&](int ks) {
        const float* Xk = Xp + ks * BK;
        #pragma unroll
        for (int i = 0; i < 4; ++i) {
            int f   = i * 512 + t;
            int row = f >> 3;           // 0..255
            int c4  = f & 7;            // 0..7
            ra[i] = *reinterpret_cast<const f32x4*>(Xk + (size_t)row * IN_DIM + c4 * 4);
        }
        const float* Wk = Wp + (size_t)(ks * BK + bn_kq * 8) * OUT_DIM + bn_n;
        #pragma unroll
        for (int e = 0; e < 8; ++e)
            rbf[e] = Wk[(size_t)e * OUT_DIM];   // lanes consecutive n -> coalesced
    };

    auto STORET = [&](int p) {
        char* AsB = reinterpret_cast<char*>(&As[p][0]);
        #pragma unroll
        for (int i = 0; i < 4; ++i) {
            int f   = i * 512 + t;
            int row = f >> 3;
            int c4  = f & 7;
            bf16x4 a4 = __builtin_convertvector(ra[i], bf16x4);
            *reinterpret_cast<bf16x4*>(AsB + row * (LDA * 2) + c4 * 8) = a4;
        }
        // B: pack 8 k-floats -> 4 k-pair words -> ONE contiguous b128
        u32x4 q;
        #pragma unroll
        for (int jj = 0; jj < 4; ++jj) {
            f32x2 pr;
            pr.x = rbf[2 * jj];         // k even (low 16)
            pr.y = rbf[2 * jj + 1];     // k odd  (high 16)
            bf16x2 pb = __builtin_convertvector(pr, bf16x2);
            q[jj] = __builtin_bit_cast(unsigned int, pb);
        }
        *reinterpret_cast<u32x4*>(&Bs[p][bn_n * LDBW + bn_kq * 4]) = q;
    };

    LOADT(0);

    for (int ks = 0; ks < NSTEP; ++ks) {
        const int p = ks & 1;

        STORET(p);                          // counted vmcnt waits on staged regs
        if (ks + 1 < NSTEP) LOADT(ks + 1);  // refill; flies across barrier+compute

        asm volatile("s_waitcnt lgkmcnt(0)" ::: "memory");
        __builtin_amdgcn_s_barrier();
        __builtin_amdgcn_sched_barrier(0);

        const char* AsB = reinterpret_cast<const char*>(&As[p][0]);
        const unsigned int* BsW = &Bs[p][0];

        // B frags: one b128 each (n-major layout, stride-80 conflict-free)
        bf16x8 bfr[4];
        #pragma unroll
        for (int ni = 0; ni < 4; ++ni) {
            int n = nbase + ni * 16 + lrow;
            u32x4 wds = *reinterpret_cast<const u32x4*>(BsW + n * LDBW + lhi * 4);
            bfr[ni] = __builtin_bit_cast(bf16x8, wds);
        }
        #pragma unroll
        for (int mi = 0; mi < 4; ++mi) {
            int r = mbase + mi * 16 + lrow;
            bf16x8 afr = *reinterpret_cast<const bf16x8*>(AsB + r * (LDA * 2) + lhi * 16);
            #pragma unroll
            for (int ni = 0; ni < 4; ++ni)
                acc[mi][ni] = __builtin_amdgcn_mfma_f32_16x16x32_bf16(
                    afr, bfr[ni], acc[mi][ni], 0, 0, 0);
        }
        // double buffer + one barrier/step: buf p next written at step ks+2,
        // after barrier ks+1 ordered all step-ks readers past it.
    }

    // epilogue: C/D layout col=lane&15, row=(lane>>4)*4+reg
    const int lcol  = lane & 15;
    const int lrow4 = (lane >> 4) * 4;
    float bv[4];
    #pragma unroll
    for (int ni = 0; ni < 4; ++ni)
        bv[ni] = bias[(size_t)c * OUT_DIM + nt * BN + nbase + ni * 16 + lcol];

    #pragma unroll
    for (int mi = 0; mi < 4; ++mi) {
        int rbase = mbase + mi * 16 + lrow4;
        #pragma unroll
        for (int ni = 0; ni < 4; ++ni) {
            int ncol = nbase + ni * 16 + lcol;
            #pragma unroll
            for (int r = 0; r < 4; ++r) {
                Op[(size_t)(rbase + r) * OUT_DIM + ncol] = acc[mi][ni][r] + bv[ni];
            }
        }
    }
}

extern "C" void kernel_launch(void* const* d_in, const int* in_sizes, int n_in,
                              void* d_out, int out_size, void* d_ws, size_t ws_size,
                              hipStream_t stream) {
    const float* x      = (const float*)d_in[0];
    const int*   cid    = (const int*)d_in[1];
    const float* weight = (const float*)d_in[2];
    const float* bias   = (const float*)d_in[3];
    float* out = (float*)d_out;

    dim3 grid(512);     // 2 blocks/CU exactly; XCD-aware remap inside kernel
    dim3 block(512);
    hipLaunchKernelGGL(cslinear_kernel, grid, block, 0, stream,
                       x, cid, weight, bias, out);
}

// Round 19
// 55.943 us; speedup vs baseline: 1.0175x; 1.0175x over previous
//
#include <hip/hip_runtime.h>

#define NUM_CATEGORIES 64
#define IN_DIM 1024
#define OUT_DIM 1024
#define BATCH 32
#define SEQ 512

#define BM 256
#define BN 256
#define BK 64
#define NSTEP (IN_DIM / BK)   // 16

#define LDA 72     // bf16 elems per A row: 128B data + 16B pad = 144B stride
#define LDBW 36    // u32 words per B n-row: 32 kp words + 4 pad = 144B stride

typedef float f32x4 __attribute__((ext_vector_type(4)));
typedef float f32x2 __attribute__((ext_vector_type(2)));
typedef unsigned int u32x4 __attribute__((ext_vector_type(4)));
typedef __bf16 bf16x2 __attribute__((ext_vector_type(2)));
typedef __bf16 bf16x4 __attribute__((ext_vector_type(4)));
typedef __bf16 bf16x8 __attribute__((ext_vector_type(8)));

// R17 (best, 49.2us) with BK=64: halves the per-step barrier/drain events
// (32 -> 16) while keeping 4 waves/SIMD TLP (R6's BK=64 failure was at
// 2 waves/SIMD). Register budget ~128 (staging 32 + acc 64 + frags + addr):
// right at the 4-wave/SIMD cap -> watch VGPR/scratch.
__global__ __launch_bounds__(1024, 1)
void cslinear_kernel(const float* __restrict__ x,
                     const int* __restrict__ cid,
                     const float* __restrict__ weight,
                     const float* __restrict__ bias,
                     float* __restrict__ out) {
    __shared__ unsigned short As[2][BM * LDA];   // 2 x 36 KB  [m][k] bf16
    __shared__ unsigned int   Bs[2][BN * LDBW];  // 2 x 36 KB  [n][kp] u32 words

    const int t    = threadIdx.x;
    const int lane = t & 63;
    const int w    = t >> 6;      // 0..15

    // XCD-aware remap: slot s -> XCD s%8; each XCD owns 4 whole batches.
    const int s    = blockIdx.x;      // 0..255
    const int xcd  = s & 7;
    const int ixd  = s >> 3;          // 0..31
    const int b    = xcd + 8 * (ixd >> 3);
    const int j    = ixd & 7;
    const int nt   = j & 3;           // 0..3
    const int mt   = j >> 2;          // 0..1

    const int c = cid[b];
    const float* Wp = weight + (size_t)c * IN_DIM * OUT_DIM + (size_t)nt * BN;
    const float* Xp = x + ((size_t)b * SEQ + (size_t)mt * BM) * IN_DIM;
    float* Op = out + ((size_t)b * SEQ + (size_t)mt * BM) * OUT_DIM + (size_t)nt * BN;

    f32x4 acc[4][4] = {};               // wave tile 64(m) x 64(n)

    const int mbase = (w >> 2) * 64;    // 0,64,128,192
    const int nbase = (w & 3) * 64;     // 0,64,128,192
    const int lrow  = lane & 15;
    const int lhi   = lane >> 4;        // 0..3

    // 1-deep staging regs
    f32x4 ra[4];                        // A: 256x64 f32 / 1024 thr = 4 f32x4
    float rbf[16];                      // B: two 8-deep k-octets of one n

    const int bn_n  = t & 255;          // B: this thread's n-column
    const int bn_kq = t >> 8;           // 0..3: k-octet group

    auto LOADT = [&](int ks) {
        const float* Xk = Xp + ks * BK;
        #pragma unroll
        for (int i = 0; i < 4; ++i) {
            int f   = i * 1024 + t;
            int row = f >> 4;           // 0..255
            int c4  = f & 15;           // 0..15
            ra[i] = *reinterpret_cast<const f32x4*>(Xk + (size_t)row * IN_DIM + c4 * 4);
        }
        // two k-octets: rows kq*8.. and 32+kq*8..
        const float* Wk0 = Wp + (size_t)(ks * BK + bn_kq * 8) * OUT_DIM + bn_n;
        const float* Wk1 = Wk0 + (size_t)32 * OUT_DIM;
        #pragma unroll
        for (int e = 0; e < 8; ++e) {
            rbf[e]     = Wk0[(size_t)e * OUT_DIM];   // coalesced (consecutive n)
            rbf[8 + e] = Wk1[(size_t)e * OUT_DIM];
        }
    };

    auto STORET = [&](int p) {
        char* AsB = reinterpret_cast<char*>(&As[p][0]);
        #pragma unroll
        for (int i = 0; i < 4; ++i) {
            int f   = i * 1024 + t;
            int row = f >> 4;
            int c4  = f & 15;
            bf16x4 a4 = __builtin_convertvector(ra[i], bf16x4);
            *reinterpret_cast<bf16x4*>(AsB + row * (LDA * 2) + c4 * 8) = a4;
        }
        // B: each octet -> 4 k-pair words -> one contiguous b128
        #pragma unroll
        for (int g = 0; g < 2; ++g) {
            u32x4 q;
            #pragma unroll
            for (int jj = 0; jj < 4; ++jj) {
                f32x2 pr;
                pr.x = rbf[g * 8 + 2 * jj];
                pr.y = rbf[g * 8 + 2 * jj + 1];
                bf16x2 pb = __builtin_convertvector(pr, bf16x2);
                q[jj] = __builtin_bit_cast(unsigned int, pb);
            }
            *reinterpret_cast<u32x4*>(&Bs[p][bn_n * LDBW + g * 16 + bn_kq * 4]) = q;
        }
    };

    LOADT(0);

    for (int ks = 0; ks < NSTEP; ++ks) {
        const int p = ks & 1;

        STORET(p);                          // counted vmcnt waits on staged regs
        if (ks + 1 < NSTEP) LOADT(ks + 1);  // refill; flies across barrier+compute

        asm volatile("s_waitcnt lgkmcnt(0)" ::: "memory");
        __builtin_amdgcn_s_barrier();
        __builtin_amdgcn_sched_barrier(0);

        const char* AsB = reinterpret_cast<const char*>(&As[p][0]);
        const unsigned int* BsW = &Bs[p][0];

        // two k-chunks of 32
        #pragma unroll
        for (int kk = 0; kk < 2; ++kk) {
            bf16x8 bfr[4];
            #pragma unroll
            for (int ni = 0; ni < 4; ++ni) {
                int n = nbase + ni * 16 + lrow;
                u32x4 wds = *reinterpret_cast<const u32x4*>(
                    BsW + n * LDBW + kk * 16 + lhi * 4);
                bfr[ni] = __builtin_bit_cast(bf16x8, wds);
            }
            #pragma unroll
            for (int mi = 0; mi < 4; ++mi) {
                int r = mbase + mi * 16 + lrow;
                bf16x8 afr = *reinterpret_cast<const bf16x8*>(
                    AsB + r * (LDA * 2) + kk * 64 + lhi * 16);
                #pragma unroll
                for (int ni = 0; ni < 4; ++ni)
                    acc[mi][ni] = __builtin_amdgcn_mfma_f32_16x16x32_bf16(
                        afr, bfr[ni], acc[mi][ni], 0, 0, 0);
            }
        }
        // double buffer + one barrier/step: buf p next written at step ks+2,
        // after barrier ks+1 ordered all step-ks readers past it.
    }

    // epilogue: C/D layout col=lane&15, row=(lane>>4)*4+reg
    const int lcol  = lane & 15;
    const int lrow4 = (lane >> 4) * 4;
    float bv[4];
    #pragma unroll
    for (int ni = 0; ni < 4; ++ni)
        bv[ni] = bias[(size_t)c * OUT_DIM + nt * BN + nbase + ni * 16 + lcol];

    #pragma unroll
    for (int mi = 0; mi < 4; ++mi) {
        int rbase = mbase + mi * 16 + lrow4;
        #pragma unroll
        for (int ni = 0; ni < 4; ++ni) {
            int ncol = nbase + ni * 16 + lcol;
            #pragma unroll
            for (int r = 0; r < 4; ++r) {
                Op[(size_t)(rbase + r) * OUT_DIM + ncol] = acc[mi][ni][r] + bv[ni];
            }
        }
    }
}

extern "C" void kernel_launch(void* const* d_in, const int* in_sizes, int n_in,
                              void* d_out, int out_size, void* d_ws, size_t ws_size,
                              hipStream_t stream) {
    const float* x      = (const float*)d_in[0];
    const int*   cid    = (const int*)d_in[1];
    const float* weight = (const float*)d_in[2];
    const float* bias   = (const float*)d_in[3];
    float* out = (float*)d_out;

    dim3 grid(256);     // flat: XCD-aware remap inside kernel; 1 block/CU
    dim3 block(1024);   // 16 waves = 4 waves/SIMD
    hipLaunchKernelGGL(cslinear_kernel, grid, block, 0, stream,
                       x, cid, weight, bias, out);
}